// Round 9
// baseline (967.128 us; speedup 1.0000x reference)
//
#include <hip/hip_runtime.h>

#define NND 100000
#define NED 50000
#define NNZC 1000000
#define MGRID 1564          // ((NND+127)/128)*2 col-halves
#define CNTB 512            // counter blocks fused into layer-1 GEMM dispatch

typedef __attribute__((ext_vector_type(8))) short bf16x8;
typedef __attribute__((ext_vector_type(4))) float f32x4;

__device__ __forceinline__ float b2f(unsigned short u) {
  union { unsigned int u; float f; } x; x.u = ((unsigned int)u) << 16; return x.f;
}
__device__ __forceinline__ float blo(unsigned int u) {
  union { unsigned int u; float f; } x; x.u = u << 16; return x.f;
}
__device__ __forceinline__ float bhi(unsigned int u) {
  union { unsigned int u; float f; } x; x.u = u & 0xffff0000u; return x.f;
}
__device__ __forceinline__ unsigned short f2b(float f) {  // RTNE fp32->bf16
  union { float f; unsigned int u; } x; x.f = f;
  unsigned int r = x.u + 0x7FFFu + ((x.u >> 16) & 1u);
  return (unsigned short)(r >> 16);
}
__device__ __forceinline__ unsigned int pk2(float lo, float hi) {
  return (unsigned int)f2b(lo) | ((unsigned int)f2b(hi) << 16);
}

// homo -> fp32; W1,W2 -> bf16 TRANSPOSED [n][k]; Wout -> fp32 zero-padded 40->64.
// Mode (0=bf16 inputs, 1=fp32) detected locally per block; block 0 publishes it.
__global__ void prep_f32(const void* __restrict__ Hin, const void* __restrict__ W1,
                         const void* __restrict__ W2, const void* __restrict__ Wout,
                         float* __restrict__ Hf, unsigned short* __restrict__ WT1b,
                         unsigned short* __restrict__ WT2b, float* __restrict__ Wf3,
                         int* __restrict__ mode) {
  __shared__ int ok;
  if (threadIdx.x == 0) ok = 1;
  __syncthreads();
  if (threadIdx.x < 64) {
    float v = b2f(((const unsigned short*)Hin)[threadIdx.x]);
    if (!(v >= 0.04f && v <= 1.1f)) ok = 0;   // benign race (same value)
  }
  __syncthreads();
  int m = ok ? 0 : 1;
  int i = blockIdx.x * 256 + threadIdx.x;
  if (i == 0) *mode = m;
  if (i < 65536) {
    int n = i >> 8, k = i & 255;
    float w1 = m ? ((const float*)W1)[k * 256 + n] : b2f(((const unsigned short*)W1)[k * 256 + n]);
    float w2 = m ? ((const float*)W2)[k * 256 + n] : b2f(((const unsigned short*)W2)[k * 256 + n]);
    WT1b[i] = f2b(w1);
    WT2b[i] = f2b(w2);
  }
  if (i < 16384) {
    int k = i >> 6, n = i & 63;
    Wf3[i] = (n < 40)
      ? (m ? ((const float*)Wout)[k * 40 + n] : b2f(((const unsigned short*)Wout)[k * 40 + n]))
      : 0.f;
  }
  if (i < NED)
    Hf[i] = m ? ((const float*)Hin)[i] : b2f(((const unsigned short*)Hin)[i]);
}

// Shared GEMM body: C[M x 256] = A[M x 256] @ W, bf16 MFMA, fp32 acc, bf16 store.
__device__ __forceinline__ void gemm_body(
    const void* __restrict__ A, bool a_fp32,
    const unsigned short* __restrict__ WT,   // [256][256] bf16, WT[n][k]
    unsigned short* __restrict__ Cb, int M, int bid) {
  __shared__ unsigned short As[128][40];
  __shared__ unsigned short Bs[128][40];
  const int t = threadIdx.x;
  const int l = t & 63;
  const int w = t >> 6;
  const int wr = w >> 1, wc = w & 1;
  const int lr16 = l & 15, lg = l >> 4;
  const int bm = bid >> 1;
  const int n0 = (bid & 1) * 128;
  const int row0 = bm * 128;

  const int tr = t >> 1, th = t & 1;
  int arow = row0 + tr; if (arow >= M) arow = M - 1;  // dup-safe, store guarded

  f32x4 acc[4][4];
#pragma unroll
  for (int m = 0; m < 4; m++)
#pragma unroll
    for (int n = 0; n < 4; n++) acc[m][n] = (f32x4){0.f, 0.f, 0.f, 0.f};

  uint4 a0, a1, b0, b1;
  auto load_regs = [&](int k0) {
    if (a_fp32) {
      const float4* ap = (const float4*)((const float*)A + (size_t)arow * 256 + k0 + th * 16);
      float4 f0 = ap[0], f1 = ap[1], f2 = ap[2], f3 = ap[3];
      a0 = make_uint4(pk2(f0.x, f0.y), pk2(f0.z, f0.w), pk2(f1.x, f1.y), pk2(f1.z, f1.w));
      a1 = make_uint4(pk2(f2.x, f2.y), pk2(f2.z, f2.w), pk2(f3.x, f3.y), pk2(f3.z, f3.w));
    } else {
      const uint4* ap = (const uint4*)((const unsigned short*)A + (size_t)arow * 256 + k0 + th * 16);
      a0 = ap[0]; a1 = ap[1];
    }
    const uint4* bp = (const uint4*)(WT + (size_t)(n0 + tr) * 256 + k0 + th * 16);
    b0 = bp[0]; b1 = bp[1];
  };

  load_regs(0);
  for (int k0 = 0; k0 < 256; k0 += 32) {
    __syncthreads();
    *(uint4*)&As[tr][th * 16]     = a0;
    *(uint4*)&As[tr][th * 16 + 8] = a1;
    *(uint4*)&Bs[tr][th * 16]     = b0;
    *(uint4*)&Bs[tr][th * 16 + 8] = b1;
    __syncthreads();
    if (k0 < 224) load_regs(k0 + 32);

    bf16x8 af[4], bfr[4];
#pragma unroll
    for (int m = 0; m < 4; m++)
      af[m] = *(const bf16x8*)&As[wr * 64 + m * 16 + lr16][lg * 8];
#pragma unroll
    for (int n = 0; n < 4; n++)
      bfr[n] = *(const bf16x8*)&Bs[wc * 64 + n * 16 + lr16][lg * 8];
#pragma unroll
    for (int m = 0; m < 4; m++)
#pragma unroll
      for (int n = 0; n < 4; n++)
        acc[m][n] = __builtin_amdgcn_mfma_f32_16x16x32_bf16(af[m], bfr[n], acc[m][n], 0, 0, 0);
  }

  // D[row=(l>>4)*4+j][col=l&15] (m89-verified); bf16 store
#pragma unroll
  for (int m = 0; m < 4; m++) {
#pragma unroll
    for (int j = 0; j < 4; j++) {
      int row = row0 + wr * 64 + m * 16 + lg * 4 + j;
      if (row < M) {
#pragma unroll
        for (int n = 0; n < 4; n++)
          Cb[(size_t)row * 256 + n0 + wc * 64 + n * 16 + lr16] = f2b(acc[m][n][j]);
      }
    }
  }
}

// Layer-1 GEMM + incidence counting via block-role split.
__global__ __launch_bounds__(256) void gemm1_cnt(
    const void* __restrict__ A, const int* __restrict__ mode,
    const unsigned short* __restrict__ WT, unsigned short* __restrict__ Cb, int M,
    const int* __restrict__ V, const int* __restrict__ E,
    int* __restrict__ cntAll, unsigned short* __restrict__ rV,
    unsigned short* __restrict__ rE) {
  const int b = blockIdx.x;
  if (b < CNTB) {
    const int STRIDE = CNTB * 256;  // 131072; 8 strides cover NNZC
    int i0 = b * 256 + threadIdx.x;
#pragma unroll
    for (int q = 0; q < 8; q++) {
      int i = i0 + q * STRIDE;
      if (i < NNZC) {
        unsigned short rv = (unsigned short)atomicAdd(&cntAll[V[i]], 1);
        unsigned short re = (unsigned short)atomicAdd(&cntAll[NND + E[i]], 1);
        rV[i] = rv;
        rE[i] = re;
      }
    }
    return;
  }
  gemm_body(A, *mode == 1, WT, Cb, M, b - CNTB);
}

// Layer-2 GEMM: bf16 internal input
__global__ __launch_bounds__(256) void gemm_bf16_k(
    const unsigned short* __restrict__ A, const unsigned short* __restrict__ WT,
    unsigned short* __restrict__ Cb, int M) {
  gemm_body(A, false, WT, Cb, M, blockIdx.x);
}

// ---- exclusive scan over cntAll (150000), 2 dispatches ----
__global__ void scan_local(const int* __restrict__ in, int* __restrict__ outExcl,
                           int* __restrict__ bsum, int n) {
  __shared__ int s[256];
  int t = threadIdx.x;
  int i = blockIdx.x * 256 + t;
  int v = (i < n) ? in[i] : 0;
  s[t] = v;
  __syncthreads();
  for (int off = 1; off < 256; off <<= 1) {
    int x = (t >= off) ? s[t - off] : 0;
    __syncthreads();
    s[t] += x;
    __syncthreads();
  }
  if (i < n) outExcl[i] = s[t] - v;
  if (t == 255) bsum[blockIdx.x] = s[255];
}

// each block self-computes its prefix over bsum[0..b) (586 values — trivial)
__global__ void scan_add2(int* __restrict__ outExcl, const int* __restrict__ bsum,
                          int n) {
  __shared__ int sm[256];
  int b = blockIdx.x, t = threadIdx.x;
  int partial = 0;
  for (int j = t; j < b; j += 256) partial += bsum[j];
  sm[t] = partial;
  __syncthreads();
  for (int off = 128; off; off >>= 1) {
    if (t < off) sm[t] += sm[t + off];
    __syncthreads();
  }
  int total = sm[0];
  int i = b * 256 + t;
  if (i < n) outExcl[i] += total;
}

// CSR fill, atomic-free. vadjH entries pack (edge_id | bf16(h)<<16).
__global__ void fill_nr(const int* __restrict__ V, const int* __restrict__ E,
                        const int* __restrict__ offAll,
                        const unsigned short* __restrict__ rV,
                        const unsigned short* __restrict__ rE,
                        const float* __restrict__ Hf,
                        unsigned int* __restrict__ vadjH,
                        int* __restrict__ eadj) {
  int i = blockIdx.x * 256 + threadIdx.x;
  if (i < NNZC) {
    int v = V[i], e = E[i];
    vadjH[offAll[v] + rV[i]] = (unsigned int)e | ((unsigned int)f2b(Hf[e]) << 16);
    eadj[offAll[NND + e] - NNZC + rE[i]] = v;
  }
}

// ---- D=256 bf16 gathers (layers 1-2), fp32 accumulation ----
__global__ __launch_bounds__(256) void edge_gather_b(
    const int* __restrict__ eoff, const int* __restrict__ cntE,
    const int* __restrict__ eadj, const unsigned int* __restrict__ XWb,
    unsigned int* __restrict__ Xeb) {
  int e = blockIdx.x * 4 + (threadIdx.x >> 6);
  int tl = threadIdx.x & 63;
  if (e >= NED) return;
  int start = eoff[e] - NNZC, n = cntE[e];
  float a0 = 0.f, a1 = 0.f, a2 = 0.f, a3 = 0.f;
  for (int c0 = 0; c0 < n; c0 += 64) {
    int m = n - c0; if (m > 64) m = 64;
    int vidx = (tl < m) ? eadj[start + c0 + tl] : 0;
#pragma unroll 4
    for (int j = 0; j < m; j++) {
      int vv = __shfl(vidx, j);
      uint2 x = *((const uint2*)(XWb + (size_t)vv * 128) + tl);
      a0 += blo(x.x); a1 += bhi(x.x); a2 += blo(x.y); a3 += bhi(x.y);
    }
  }
  float inv = (n > 0) ? 1.0f / (float)n : 0.f;
  uint2 o;
  o.x = pk2(a0 * inv, a1 * inv);
  o.y = pk2(a2 * inv, a3 * inv);
  *((uint2*)(Xeb + (size_t)e * 128) + tl) = o;
}

// out = L2norm(XW[v] + (1/sum h)*sum h_e*Xe[e]) + relu.
// Outputs (nullable): bf16 Zb; fp32 outf; fused layer-3 GEMM row @ W3 -> bf16 XW64.
__global__ __launch_bounds__(256) void node_gather_norm_b(
    const int* __restrict__ voff, const int* __restrict__ degV,
    const unsigned int* __restrict__ vadjH,
    const unsigned int* __restrict__ Xeb, const unsigned int* __restrict__ XWb,
    unsigned int* __restrict__ Zb, float* __restrict__ outf,
    const float* __restrict__ W3, unsigned short* __restrict__ XW64) {
  __shared__ float zrow[4][256];
  int wid = threadIdx.x >> 6;
  int v = blockIdx.x * 4 + wid;          // grid exact: v < NND always
  int tl = threadIdx.x & 63;
  int start = voff[v], n = degV[v];
  uint2 r = *((const uint2*)(XWb + (size_t)v * 128) + tl);
  float a0 = blo(r.x), a1 = bhi(r.x), a2 = blo(r.y), a3 = bhi(r.y);
  float g0 = 0.f, g1 = 0.f, g2 = 0.f, g3 = 0.f, hsum = 0.f;
  for (int c0 = 0; c0 < n; c0 += 64) {
    int m = n - c0; if (m > 64) m = 64;
    unsigned int pk = (tl < m) ? vadjH[start + c0 + tl] : 0u;
    hsum += b2f((unsigned short)(pk >> 16));
#pragma unroll 4
    for (int j = 0; j < m; j++) {
      unsigned int u = (unsigned int)__shfl((int)pk, j);
      int ee = (int)(u & 0xffffu);
      float a = b2f((unsigned short)(u >> 16));
      uint2 x = *((const uint2*)(Xeb + (size_t)ee * 128) + tl);
      g0 += a * blo(x.x); g1 += a * bhi(x.x);
      g2 += a * blo(x.y); g3 += a * bhi(x.y);
    }
  }
#pragma unroll
  for (int off = 32; off; off >>= 1) hsum += __shfl_xor(hsum, off);
  float inv_att = (hsum > 0.f) ? 1.0f / hsum : 0.f;
  a0 += inv_att * g0; a1 += inv_att * g1;
  a2 += inv_att * g2; a3 += inv_att * g3;
  float ss = a0 * a0 + a1 * a1 + a2 * a2 + a3 * a3;
#pragma unroll
  for (int off = 32; off; off >>= 1) ss += __shfl_xor(ss, off);
  float sc = (ss > 0.f) ? (1.0f / sqrtf(ss)) : 0.f;
  a0 = fmaxf(a0 * sc, 0.f); a1 = fmaxf(a1 * sc, 0.f);
  a2 = fmaxf(a2 * sc, 0.f); a3 = fmaxf(a3 * sc, 0.f);
  if (Zb) {
    uint2 o; o.x = pk2(a0, a1); o.y = pk2(a2, a3);
    *((uint2*)(Zb + (size_t)v * 128) + tl) = o;
  }
  if (outf) *((float4*)(outf + (size_t)v * 256) + tl) = make_float4(a0, a1, a2, a3);
  if (W3) {
    // fused layer-3 GEMM: XW64[v][tl] = sum_k Zrow[k] * W3[k][tl]
    *(float4*)&zrow[wid][tl * 4] = make_float4(a0, a1, a2, a3);
    __syncthreads();   // uniform (no early returns in this kernel)
    float out = 0.f;
#pragma unroll 4
    for (int k = 0; k < 256; k += 4) {
      float4 z4 = *(const float4*)&zrow[wid][k];     // LDS broadcast (free)
      out += z4.x * W3[(k + 0) * 64 + tl];           // 256B/wave coalesced, L2-hot
      out += z4.y * W3[(k + 1) * 64 + tl];
      out += z4.z * W3[(k + 2) * 64 + tl];
      out += z4.w * W3[(k + 3) * 64 + tl];
    }
    XW64[(size_t)v * 64 + tl] = f2b(out);
  }
}

// ---- D=64 bf16 gathers (layer 3) ----
__global__ __launch_bounds__(256) void edge_gather_64(
    const int* __restrict__ eoff, const int* __restrict__ cntE,
    const int* __restrict__ eadj, const unsigned short* __restrict__ XW64,
    unsigned short* __restrict__ Xe64) {
  int e = blockIdx.x * 4 + (threadIdx.x >> 6);
  int tl = threadIdx.x & 63;
  if (e >= NED) return;
  int start = eoff[e] - NNZC, n = cntE[e];
  float ax = 0.f;
  for (int c0 = 0; c0 < n; c0 += 64) {
    int m = n - c0; if (m > 64) m = 64;
    int vidx = (tl < m) ? eadj[start + c0 + tl] : 0;
#pragma unroll 4
    for (int j = 0; j < m; j++) {
      int vv = __shfl(vidx, j);
      ax += b2f(XW64[(size_t)vv * 64 + tl]);
    }
  }
  float inv = (n > 0) ? 1.0f / (float)n : 0.f;
  Xe64[(size_t)e * 64 + tl] = f2b(ax * inv);
}

__global__ __launch_bounds__(256) void node_gather_norm_64(
    const int* __restrict__ voff, const int* __restrict__ degV,
    const unsigned int* __restrict__ vadjH,
    const unsigned short* __restrict__ Xe64, const unsigned short* __restrict__ XW64,
    float* __restrict__ out) {
  int v = blockIdx.x * 4 + (threadIdx.x >> 6);
  int tl = threadIdx.x & 63;
  if (v >= NND) return;
  int start = voff[v], n = degV[v];
  float ax = b2f(XW64[(size_t)v * 64 + tl]);
  float gx = 0.f, hsum = 0.f;
  for (int c0 = 0; c0 < n; c0 += 64) {
    int m = n - c0; if (m > 64) m = 64;
    unsigned int pk = (tl < m) ? vadjH[start + c0 + tl] : 0u;
    hsum += b2f((unsigned short)(pk >> 16));
#pragma unroll 4
    for (int j = 0; j < m; j++) {
      unsigned int u = (unsigned int)__shfl((int)pk, j);
      int ee = (int)(u & 0xffffu);
      float a = b2f((unsigned short)(u >> 16));
      gx += a * b2f(Xe64[(size_t)ee * 64 + tl]);
    }
  }
#pragma unroll
  for (int off = 32; off; off >>= 1) hsum += __shfl_xor(hsum, off);
  float inv_att = (hsum > 0.f) ? 1.0f / hsum : 0.f;
  ax += inv_att * gx;
  float ss = ax * ax;
#pragma unroll
  for (int off = 32; off; off >>= 1) ss += __shfl_xor(ss, off);
  float sc = (ss > 0.f) ? (1.0f / sqrtf(ss)) : 0.f;
  ax *= sc;
  if (tl < 40) out[(size_t)v * 40 + tl] = ax;
}

__global__ void sentinel_k(float* __restrict__ out, long n, float val) {
  long i = (long)blockIdx.x * 256 + threadIdx.x;
  long stride = (long)gridDim.x * 256;
  for (; i < n; i += stride) out[i] = val;
}

extern "C" void kernel_launch(void* const* d_in, const int* in_sizes, int n_in,
                              void* d_out, int out_size, void* d_ws, size_t ws_size,
                              hipStream_t stream) {
  const void* Xin  = d_in[0];
  const int*  V    = (const int*)d_in[1];
  const int*  E    = (const int*)d_in[2];
  const void* Hin  = d_in[3];
  const void* W1   = d_in[4];
  const void* W2   = d_in[5];
  const void* Wout = d_in[6];
  float* Zout = (float*)d_out;                       // [100000][256] fp32
  float* Xout = Zout + (size_t)NND * 256;            // [100000][40]  fp32
  (void)in_sizes; (void)n_in;

  char* base = (char*)d_ws;
  size_t o = 0;
  auto carve = [&](size_t bytes) -> char* {
    char* p = base + o;
    o += (bytes + 255) & ~(size_t)255;
    return p;
  };
  unsigned int*  XWb  = (unsigned int*)carve((size_t)NND * 256 * 2);   // bf16, 51.2 MB
  unsigned int*  Xeb  = (unsigned int*)carve((size_t)NED * 256 * 2);   // bf16, 25.6 MB
  unsigned int*  Zb   = (unsigned int*)carve((size_t)NND * 256 * 2);   // bf16, 51.2 MB
  unsigned short* XW64 = (unsigned short*)carve((size_t)NND * 64 * 2); // 12.8 MB
  unsigned short* Xe64 = (unsigned short*)carve((size_t)NED * 64 * 2); // 6.4 MB
  float* Hf    = (float*)carve((size_t)NED * 4);
  int*   cntAll = (int*)carve((size_t)(NND + NED) * 4);   // degV | cntE
  int*   offAll = (int*)carve((size_t)(NND + NED) * 4);   // voff | eoff
  unsigned short* rV = (unsigned short*)carve((size_t)NNZC * 2);  // 2 MB
  unsigned short* rE = (unsigned short*)carve((size_t)NNZC * 2);  // 2 MB
  unsigned int* vadjH = (unsigned int*)carve((size_t)NNZC * 4);   // 4 MB
  int*   eadj  = (int*)carve((size_t)NNZC * 4);                   // 4 MB
  int*   bsum  = (int*)carve(1024 * 4);
  unsigned short* WT1b = (unsigned short*)carve(65536 * 2);
  unsigned short* WT2b = (unsigned short*)carve(65536 * 2);
  float* Wf3   = (float*)carve(16384 * 4);
  int*   mode  = (int*)carve(256);
  const size_t NEED = o;   // ~161 MB

  if (ws_size < NEED) {  // decodable failure: absmax ≈ 77
    sentinel_k<<<4096, 256, 0, stream>>>(Zout, (long)out_size, 77.0f);
    return;
  }

  const int NCNT = NND + NED;                // 150000
  const int NBC = (NCNT + 255) / 256;        // 586
  const int FILL_GRID = (NNZC + 255) / 256;
  const int EG_GRID = (NED + 3) / 4;
  const int NG_GRID = (NND + 3) / 4;         // 25000, grid exact (4 nodes/block)

  const int* voff = offAll;
  const int* eoff = offAll + NND;
  const int* degV = cntAll;
  const int* cntE = cntAll + NND;

  prep_f32<<<256, 256, 0, stream>>>(Hin, W1, W2, Wout, Hf, WT1b, WT2b, Wf3, mode);
  hipMemsetAsync(cntAll, 0, (size_t)NCNT * 4, stream);

  // ---- layer-1 GEMM with counting on dedicated blocks
  gemm1_cnt<<<CNTB + MGRID, 256, 0, stream>>>(Xin, mode, WT1b, (unsigned short*)XWb,
                                              NND, V, E, cntAll, rV, rE);

  scan_local<<<NBC, 256, 0, stream>>>(cntAll, offAll, bsum, NCNT);
  scan_add2<<<NBC, 256, 0, stream>>>(offAll, bsum, NCNT);
  fill_nr<<<FILL_GRID, 256, 0, stream>>>(V, E, offAll, rV, rE, Hf, vadjH, eadj);

  // ---- layer 1 gathers (bf16 Zb only)
  edge_gather_b<<<EG_GRID, 256, 0, stream>>>(eoff, cntE, eadj, XWb, Xeb);
  node_gather_norm_b<<<NG_GRID, 256, 0, stream>>>(voff, degV, vadjH, Xeb, XWb,
                                                  Zb, nullptr, nullptr, nullptr);

  // ---- layer 2 (outputs: graded fp32 Zout + fused layer-3 GEMM -> bf16 XW64)
  gemm_bf16_k<<<MGRID, 256, 0, stream>>>((const unsigned short*)Zb, WT2b,
                                         (unsigned short*)XWb, NND);
  edge_gather_b<<<EG_GRID, 256, 0, stream>>>(eoff, cntE, eadj, XWb, Xeb);
  node_gather_norm_b<<<NG_GRID, 256, 0, stream>>>(voff, degV, vadjH, Xeb, XWb,
                                                  nullptr, Zout, Wf3, XW64);

  // ---- layer 3 gathers (bf16 intermediates, fp32 math, fp32 graded Xout)
  edge_gather_64<<<EG_GRID, 256, 0, stream>>>(eoff, cntE, eadj, XW64, Xe64);
  node_gather_norm_64<<<NG_GRID, 256, 0, stream>>>(voff, degV, vadjH, Xe64, XW64, Xout);
}

// Round 10
// 853.564 us; speedup vs baseline: 1.1330x; 1.1330x over previous
//
#include <hip/hip_runtime.h>

#define NND 100000
#define NED 50000
#define NNZC 1000000
#define MGRID 1564          // ((NND+127)/128)*2 col-halves
#define CNTB 512            // counter blocks fused into layer-1 GEMM dispatch
#define FILLB 512           // vadjH-fill blocks fused into eg1 dispatch

typedef __attribute__((ext_vector_type(8))) short bf16x8;
typedef __attribute__((ext_vector_type(4))) float f32x4;

__device__ __forceinline__ float b2f(unsigned short u) {
  union { unsigned int u; float f; } x; x.u = ((unsigned int)u) << 16; return x.f;
}
__device__ __forceinline__ float blo(unsigned int u) {
  union { unsigned int u; float f; } x; x.u = u << 16; return x.f;
}
__device__ __forceinline__ float bhi(unsigned int u) {
  union { unsigned int u; float f; } x; x.u = u & 0xffff0000u; return x.f;
}
__device__ __forceinline__ unsigned short f2b(float f) {  // RTNE fp32->bf16
  union { float f; unsigned int u; } x; x.f = f;
  unsigned int r = x.u + 0x7FFFu + ((x.u >> 16) & 1u);
  return (unsigned short)(r >> 16);
}
__device__ __forceinline__ unsigned int pk2(float lo, float hi) {
  return (unsigned int)f2b(lo) | ((unsigned int)f2b(hi) << 16);
}

// homo -> fp32; W1,W2 -> bf16 T [n][k]; Wout -> bf16 T [64][256] zero-padded.
// Mode (0=bf16 inputs, 1=fp32) detected locally per block; block 0 publishes it.
__global__ void prep_f32(const void* __restrict__ Hin, const void* __restrict__ W1,
                         const void* __restrict__ W2, const void* __restrict__ Wout,
                         float* __restrict__ Hf, unsigned short* __restrict__ WT1b,
                         unsigned short* __restrict__ WT2b,
                         unsigned short* __restrict__ WT3b,
                         int* __restrict__ mode) {
  __shared__ int ok;
  if (threadIdx.x == 0) ok = 1;
  __syncthreads();
  if (threadIdx.x < 64) {
    float v = b2f(((const unsigned short*)Hin)[threadIdx.x]);
    if (!(v >= 0.04f && v <= 1.1f)) ok = 0;   // benign race (same value)
  }
  __syncthreads();
  int m = ok ? 0 : 1;
  int i = blockIdx.x * 256 + threadIdx.x;
  if (i == 0) *mode = m;
  if (i < 65536) {
    int n = i >> 8, k = i & 255;
    float w1 = m ? ((const float*)W1)[k * 256 + n] : b2f(((const unsigned short*)W1)[k * 256 + n]);
    float w2 = m ? ((const float*)W2)[k * 256 + n] : b2f(((const unsigned short*)W2)[k * 256 + n]);
    WT1b[i] = f2b(w1);
    WT2b[i] = f2b(w2);
  }
  if (i < 16384) {  // WT3b[n][k], n<64 (cols 40..63 zero), k<256
    int n = i >> 8, k = i & 255;
    float w3 = (n < 40)
      ? (m ? ((const float*)Wout)[k * 40 + n] : b2f(((const unsigned short*)Wout)[k * 40 + n]))
      : 0.f;
    WT3b[i] = f2b(w3);
  }
  if (i < NED)
    Hf[i] = m ? ((const float*)Hin)[i] : b2f(((const unsigned short*)Hin)[i]);
}

// Shared GEMM body: C[M x 256] = A[M x 256] @ W, bf16 MFMA, fp32 acc, bf16 store.
__device__ __forceinline__ void gemm_body(
    const void* __restrict__ A, bool a_fp32,
    const unsigned short* __restrict__ WT,   // [256][256] bf16, WT[n][k]
    unsigned short* __restrict__ Cb, int M, int bid) {
  __shared__ unsigned short As[128][40];
  __shared__ unsigned short Bs[128][40];
  const int t = threadIdx.x;
  const int l = t & 63;
  const int w = t >> 6;
  const int wr = w >> 1, wc = w & 1;
  const int lr16 = l & 15, lg = l >> 4;
  const int bm = bid >> 1;
  const int n0 = (bid & 1) * 128;
  const int row0 = bm * 128;

  const int tr = t >> 1, th = t & 1;
  int arow = row0 + tr; if (arow >= M) arow = M - 1;  // dup-safe, store guarded

  f32x4 acc[4][4];
#pragma unroll
  for (int m = 0; m < 4; m++)
#pragma unroll
    for (int n = 0; n < 4; n++) acc[m][n] = (f32x4){0.f, 0.f, 0.f, 0.f};

  uint4 a0, a1, b0, b1;
  auto load_regs = [&](int k0) {
    if (a_fp32) {
      const float4* ap = (const float4*)((const float*)A + (size_t)arow * 256 + k0 + th * 16);
      float4 f0 = ap[0], f1 = ap[1], f2 = ap[2], f3 = ap[3];
      a0 = make_uint4(pk2(f0.x, f0.y), pk2(f0.z, f0.w), pk2(f1.x, f1.y), pk2(f1.z, f1.w));
      a1 = make_uint4(pk2(f2.x, f2.y), pk2(f2.z, f2.w), pk2(f3.x, f3.y), pk2(f3.z, f3.w));
    } else {
      const uint4* ap = (const uint4*)((const unsigned short*)A + (size_t)arow * 256 + k0 + th * 16);
      a0 = ap[0]; a1 = ap[1];
    }
    const uint4* bp = (const uint4*)(WT + (size_t)(n0 + tr) * 256 + k0 + th * 16);
    b0 = bp[0]; b1 = bp[1];
  };

  load_regs(0);
  for (int k0 = 0; k0 < 256; k0 += 32) {
    __syncthreads();
    *(uint4*)&As[tr][th * 16]     = a0;
    *(uint4*)&As[tr][th * 16 + 8] = a1;
    *(uint4*)&Bs[tr][th * 16]     = b0;
    *(uint4*)&Bs[tr][th * 16 + 8] = b1;
    __syncthreads();
    if (k0 < 224) load_regs(k0 + 32);

    bf16x8 af[4], bfr[4];
#pragma unroll
    for (int m = 0; m < 4; m++)
      af[m] = *(const bf16x8*)&As[wr * 64 + m * 16 + lr16][lg * 8];
#pragma unroll
    for (int n = 0; n < 4; n++)
      bfr[n] = *(const bf16x8*)&Bs[wc * 64 + n * 16 + lr16][lg * 8];
#pragma unroll
    for (int m = 0; m < 4; m++)
#pragma unroll
      for (int n = 0; n < 4; n++)
        acc[m][n] = __builtin_amdgcn_mfma_f32_16x16x32_bf16(af[m], bfr[n], acc[m][n], 0, 0, 0);
  }

  // D[row=(l>>4)*4+j][col=l&15] (m89-verified); bf16 store
#pragma unroll
  for (int m = 0; m < 4; m++) {
#pragma unroll
    for (int j = 0; j < 4; j++) {
      int row = row0 + wr * 64 + m * 16 + lg * 4 + j;
      if (row < M) {
#pragma unroll
        for (int n = 0; n < 4; n++)
          Cb[(size_t)row * 256 + n0 + wc * 64 + n * 16 + lr16] = f2b(acc[m][n][j]);
      }
    }
  }
}

// Layer-1 GEMM + incidence counting via block-role split.
__global__ __launch_bounds__(256) void gemm1_cnt(
    const void* __restrict__ A, const int* __restrict__ mode,
    const unsigned short* __restrict__ WT, unsigned short* __restrict__ Cb, int M,
    const int* __restrict__ V, const int* __restrict__ E,
    int* __restrict__ cntAll, unsigned short* __restrict__ rV,
    unsigned short* __restrict__ rE) {
  const int b = blockIdx.x;
  if (b < CNTB) {
    const int STRIDE = CNTB * 256;  // 131072; 8 strides cover NNZC
    int i0 = b * 256 + threadIdx.x;
#pragma unroll
    for (int q = 0; q < 8; q++) {
      int i = i0 + q * STRIDE;
      if (i < NNZC) {
        unsigned short rv = (unsigned short)atomicAdd(&cntAll[V[i]], 1);
        unsigned short re = (unsigned short)atomicAdd(&cntAll[NND + E[i]], 1);
        rV[i] = rv;
        rE[i] = re;
      }
    }
    return;
  }
  gemm_body(A, *mode == 1, WT, Cb, M, b - CNTB);
}

// Layer-2 GEMM: bf16 internal input
__global__ __launch_bounds__(256) void gemm_bf16_k(
    const unsigned short* __restrict__ A, const unsigned short* __restrict__ WT,
    unsigned short* __restrict__ Cb, int M) {
  gemm_body(A, false, WT, Cb, M, blockIdx.x);
}

// Layer-3 MFMA GEMM: C[M x 64] = A_bf16[M x 256] @ W3 (WT3b[64][256]).
// Tile 128x64, 4 waves (2Mx2N), per-wave 64x32 (acc[4][2]).
__global__ __launch_bounds__(256) void gemm3_mfma(
    const unsigned short* __restrict__ A, const unsigned short* __restrict__ WT,
    unsigned short* __restrict__ Cb, int M) {
  __shared__ unsigned short As[128][40];
  __shared__ unsigned short Bs[64][40];
  const int t = threadIdx.x;
  const int l = t & 63;
  const int w = t >> 6;
  const int wr = w >> 1, wc = w & 1;
  const int lr16 = l & 15, lg = l >> 4;
  const int row0 = blockIdx.x * 128;

  const int tr = t >> 1, th = t & 1;     // A staging: row, 16-elem half
  const int br = t >> 2, bq = t & 3;     // B staging: row, 8-elem quarter
  int arow = row0 + tr; if (arow >= M) arow = M - 1;

  f32x4 acc[4][2];
#pragma unroll
  for (int m = 0; m < 4; m++)
#pragma unroll
    for (int n = 0; n < 2; n++) acc[m][n] = (f32x4){0.f, 0.f, 0.f, 0.f};

  uint4 a0, a1, b0;
  auto load_regs = [&](int k0) {
    const uint4* ap = (const uint4*)(A + (size_t)arow * 256 + k0 + th * 16);
    a0 = ap[0]; a1 = ap[1];
    b0 = *(const uint4*)(WT + (size_t)br * 256 + k0 + bq * 8);
  };

  load_regs(0);
  for (int k0 = 0; k0 < 256; k0 += 32) {
    __syncthreads();
    *(uint4*)&As[tr][th * 16]     = a0;
    *(uint4*)&As[tr][th * 16 + 8] = a1;
    *(uint4*)&Bs[br][bq * 8]      = b0;
    __syncthreads();
    if (k0 < 224) load_regs(k0 + 32);

    bf16x8 af[4], bfr[2];
#pragma unroll
    for (int m = 0; m < 4; m++)
      af[m] = *(const bf16x8*)&As[wr * 64 + m * 16 + lr16][lg * 8];
#pragma unroll
    for (int n = 0; n < 2; n++)
      bfr[n] = *(const bf16x8*)&Bs[wc * 32 + n * 16 + lr16][lg * 8];
#pragma unroll
    for (int m = 0; m < 4; m++)
#pragma unroll
      for (int n = 0; n < 2; n++)
        acc[m][n] = __builtin_amdgcn_mfma_f32_16x16x32_bf16(af[m], bfr[n], acc[m][n], 0, 0, 0);
  }

#pragma unroll
  for (int m = 0; m < 4; m++) {
#pragma unroll
    for (int j = 0; j < 4; j++) {
      int row = row0 + wr * 64 + m * 16 + lg * 4 + j;
      if (row < M) {
#pragma unroll
        for (int n = 0; n < 2; n++)
          Cb[(size_t)row * 64 + wc * 32 + n * 16 + lr16] = f2b(acc[m][n][j]);
      }
    }
  }
}

// ---- exclusive scan over cntAll (150000), 2 dispatches ----
__global__ void scan_local(const int* __restrict__ in, int* __restrict__ outExcl,
                           int* __restrict__ bsum, int n) {
  __shared__ int s[256];
  int t = threadIdx.x;
  int i = blockIdx.x * 256 + t;
  int v = (i < n) ? in[i] : 0;
  s[t] = v;
  __syncthreads();
  for (int off = 1; off < 256; off <<= 1) {
    int x = (t >= off) ? s[t - off] : 0;
    __syncthreads();
    s[t] += x;
    __syncthreads();
  }
  if (i < n) outExcl[i] = s[t] - v;
  if (t == 255) bsum[blockIdx.x] = s[255];
}

// each block self-computes its prefix over bsum[0..b) (586 values — trivial)
__global__ void scan_add2(int* __restrict__ outExcl, const int* __restrict__ bsum,
                          int n) {
  __shared__ int sm[256];
  int b = blockIdx.x, t = threadIdx.x;
  int partial = 0;
  for (int j = t; j < b; j += 256) partial += bsum[j];
  sm[t] = partial;
  __syncthreads();
  for (int off = 128; off; off >>= 1) {
    if (t < off) sm[t] += sm[t + off];
    __syncthreads();
  }
  int total = sm[0];
  int i = b * 256 + t;
  if (i < n) outExcl[i] += total;
}

// eadj fill only (eg1 depends on it -> own dispatch)
__global__ void fill_e(const int* __restrict__ V, const int* __restrict__ E,
                       const int* __restrict__ offAll,
                       const unsigned short* __restrict__ rE,
                       int* __restrict__ eadj) {
  int i = blockIdx.x * 256 + threadIdx.x;
  if (i < NNZC) {
    int e = E[i];
    eadj[offAll[NND + e] - NNZC + rE[i]] = V[i];
  }
}

// ---- D=256 bf16 edge gather; leading FILLV blocks fill vadjH (only ng reads it)
__global__ __launch_bounds__(256) void edge_gather_b(
    const int* __restrict__ eoff, const int* __restrict__ cntE,
    const int* __restrict__ eadj, const unsigned int* __restrict__ XWb,
    unsigned int* __restrict__ Xeb, int fillv,
    const int* __restrict__ V, const int* __restrict__ E,
    const int* __restrict__ offAll, const unsigned short* __restrict__ rV,
    const float* __restrict__ Hf, unsigned int* __restrict__ vadjH) {
  if (blockIdx.x < fillv) {
    const int stride = fillv * 256;
    for (int i = blockIdx.x * 256 + threadIdx.x; i < NNZC; i += stride) {
      int v = V[i], e = E[i];
      vadjH[offAll[v] + rV[i]] = (unsigned int)e | ((unsigned int)f2b(Hf[e]) << 16);
    }
    return;
  }
  int e = (blockIdx.x - fillv) * 4 + (threadIdx.x >> 6);
  int tl = threadIdx.x & 63;
  if (e >= NED) return;
  int start = eoff[e] - NNZC, n = cntE[e];
  float a0 = 0.f, a1 = 0.f, a2 = 0.f, a3 = 0.f;
  for (int c0 = 0; c0 < n; c0 += 64) {
    int m = n - c0; if (m > 64) m = 64;
    int vidx = (tl < m) ? eadj[start + c0 + tl] : 0;
#pragma unroll 4
    for (int j = 0; j < m; j++) {
      int vv = __shfl(vidx, j);
      uint2 x = *((const uint2*)(XWb + (size_t)vv * 128) + tl);
      a0 += blo(x.x); a1 += bhi(x.x); a2 += blo(x.y); a3 += bhi(x.y);
    }
  }
  float inv = (n > 0) ? 1.0f / (float)n : 0.f;
  uint2 o;
  o.x = pk2(a0 * inv, a1 * inv);
  o.y = pk2(a2 * inv, a3 * inv);
  *((uint2*)(Xeb + (size_t)e * 128) + tl) = o;
}

// out = L2norm(XW[v] + (1/sum h)*sum h_e*Xe[e]) + relu. Nullable bf16/fp32 outs.
__global__ __launch_bounds__(256) void node_gather_norm_b(
    const int* __restrict__ voff, const int* __restrict__ degV,
    const unsigned int* __restrict__ vadjH,
    const unsigned int* __restrict__ Xeb, const unsigned int* __restrict__ XWb,
    unsigned int* __restrict__ Zb, float* __restrict__ outf) {
  int v = blockIdx.x * 4 + (threadIdx.x >> 6);
  int tl = threadIdx.x & 63;
  if (v >= NND) return;
  int start = voff[v], n = degV[v];
  uint2 r = *((const uint2*)(XWb + (size_t)v * 128) + tl);
  float a0 = blo(r.x), a1 = bhi(r.x), a2 = blo(r.y), a3 = bhi(r.y);
  float g0 = 0.f, g1 = 0.f, g2 = 0.f, g3 = 0.f, hsum = 0.f;
  for (int c0 = 0; c0 < n; c0 += 64) {
    int m = n - c0; if (m > 64) m = 64;
    unsigned int pk = (tl < m) ? vadjH[start + c0 + tl] : 0u;
    hsum += b2f((unsigned short)(pk >> 16));
#pragma unroll 4
    for (int j = 0; j < m; j++) {
      unsigned int u = (unsigned int)__shfl((int)pk, j);
      int ee = (int)(u & 0xffffu);
      float a = b2f((unsigned short)(u >> 16));
      uint2 x = *((const uint2*)(Xeb + (size_t)ee * 128) + tl);
      g0 += a * blo(x.x); g1 += a * bhi(x.x);
      g2 += a * blo(x.y); g3 += a * bhi(x.y);
    }
  }
#pragma unroll
  for (int off = 32; off; off >>= 1) hsum += __shfl_xor(hsum, off);
  float inv_att = (hsum > 0.f) ? 1.0f / hsum : 0.f;
  a0 += inv_att * g0; a1 += inv_att * g1;
  a2 += inv_att * g2; a3 += inv_att * g3;
  float ss = a0 * a0 + a1 * a1 + a2 * a2 + a3 * a3;
#pragma unroll
  for (int off = 32; off; off >>= 1) ss += __shfl_xor(ss, off);
  float sc = (ss > 0.f) ? (1.0f / sqrtf(ss)) : 0.f;
  a0 = fmaxf(a0 * sc, 0.f); a1 = fmaxf(a1 * sc, 0.f);
  a2 = fmaxf(a2 * sc, 0.f); a3 = fmaxf(a3 * sc, 0.f);
  if (Zb) {
    uint2 o; o.x = pk2(a0, a1); o.y = pk2(a2, a3);
    *((uint2*)(Zb + (size_t)v * 128) + tl) = o;
  }
  if (outf) *((float4*)(outf + (size_t)v * 256) + tl) = make_float4(a0, a1, a2, a3);
}

// ---- D=64 bf16 gathers (layer 3) ----
__global__ __launch_bounds__(256) void edge_gather_64(
    const int* __restrict__ eoff, const int* __restrict__ cntE,
    const int* __restrict__ eadj, const unsigned short* __restrict__ XW64,
    unsigned short* __restrict__ Xe64) {
  int e = blockIdx.x * 4 + (threadIdx.x >> 6);
  int tl = threadIdx.x & 63;
  if (e >= NED) return;
  int start = eoff[e] - NNZC, n = cntE[e];
  float ax = 0.f;
  for (int c0 = 0; c0 < n; c0 += 64) {
    int m = n - c0; if (m > 64) m = 64;
    int vidx = (tl < m) ? eadj[start + c0 + tl] : 0;
#pragma unroll 4
    for (int j = 0; j < m; j++) {
      int vv = __shfl(vidx, j);
      ax += b2f(XW64[(size_t)vv * 64 + tl]);
    }
  }
  float inv = (n > 0) ? 1.0f / (float)n : 0.f;
  Xe64[(size_t)e * 64 + tl] = f2b(ax * inv);
}

__global__ __launch_bounds__(256) void node_gather_norm_64(
    const int* __restrict__ voff, const int* __restrict__ degV,
    const unsigned int* __restrict__ vadjH,
    const unsigned short* __restrict__ Xe64, const unsigned short* __restrict__ XW64,
    float* __restrict__ out) {
  int v = blockIdx.x * 4 + (threadIdx.x >> 6);
  int tl = threadIdx.x & 63;
  if (v >= NND) return;
  int start = voff[v], n = degV[v];
  float ax = b2f(XW64[(size_t)v * 64 + tl]);
  float gx = 0.f, hsum = 0.f;
  for (int c0 = 0; c0 < n; c0 += 64) {
    int m = n - c0; if (m > 64) m = 64;
    unsigned int pk = (tl < m) ? vadjH[start + c0 + tl] : 0u;
    hsum += b2f((unsigned short)(pk >> 16));
#pragma unroll 4
    for (int j = 0; j < m; j++) {
      unsigned int u = (unsigned int)__shfl((int)pk, j);
      int ee = (int)(u & 0xffffu);
      float a = b2f((unsigned short)(u >> 16));
      gx += a * b2f(Xe64[(size_t)ee * 64 + tl]);
    }
  }
#pragma unroll
  for (int off = 32; off; off >>= 1) hsum += __shfl_xor(hsum, off);
  float inv_att = (hsum > 0.f) ? 1.0f / hsum : 0.f;
  ax += inv_att * gx;
  float ss = ax * ax;
#pragma unroll
  for (int off = 32; off; off >>= 1) ss += __shfl_xor(ss, off);
  float sc = (ss > 0.f) ? (1.0f / sqrtf(ss)) : 0.f;
  ax *= sc;
  if (tl < 40) out[(size_t)v * 40 + tl] = ax;
}

__global__ void sentinel_k(float* __restrict__ out, long n, float val) {
  long i = (long)blockIdx.x * 256 + threadIdx.x;
  long stride = (long)gridDim.x * 256;
  for (; i < n; i += stride) out[i] = val;
}

extern "C" void kernel_launch(void* const* d_in, const int* in_sizes, int n_in,
                              void* d_out, int out_size, void* d_ws, size_t ws_size,
                              hipStream_t stream) {
  const void* Xin  = d_in[0];
  const int*  V    = (const int*)d_in[1];
  const int*  E    = (const int*)d_in[2];
  const void* Hin  = d_in[3];
  const void* W1   = d_in[4];
  const void* W2   = d_in[5];
  const void* Wout = d_in[6];
  float* Zout = (float*)d_out;                       // [100000][256] fp32
  float* Xout = Zout + (size_t)NND * 256;            // [100000][40]  fp32
  (void)in_sizes; (void)n_in;

  char* base = (char*)d_ws;
  size_t o = 0;
  auto carve = [&](size_t bytes) -> char* {
    char* p = base + o;
    o += (bytes + 255) & ~(size_t)255;
    return p;
  };
  unsigned int*  XWb  = (unsigned int*)carve((size_t)NND * 256 * 2);   // bf16, 51.2 MB
  unsigned int*  Xeb  = (unsigned int*)carve((size_t)NED * 256 * 2);   // bf16, 25.6 MB
  unsigned int*  Zb   = (unsigned int*)carve((size_t)NND * 256 * 2);   // bf16, 51.2 MB
  unsigned short* XW64 = (unsigned short*)carve((size_t)NND * 64 * 2); // 12.8 MB
  unsigned short* Xe64 = (unsigned short*)carve((size_t)NED * 64 * 2); // 6.4 MB
  float* Hf    = (float*)carve((size_t)NED * 4);
  int*   cntAll = (int*)carve((size_t)(NND + NED) * 4);   // degV | cntE
  int*   offAll = (int*)carve((size_t)(NND + NED) * 4);   // voff | eoff
  unsigned short* rV = (unsigned short*)carve((size_t)NNZC * 2);  // 2 MB
  unsigned short* rE = (unsigned short*)carve((size_t)NNZC * 2);  // 2 MB
  unsigned int* vadjH = (unsigned int*)carve((size_t)NNZC * 4);   // 4 MB
  int*   eadj  = (int*)carve((size_t)NNZC * 4);                   // 4 MB
  int*   bsum  = (int*)carve(1024 * 4);
  unsigned short* WT1b = (unsigned short*)carve(65536 * 2);
  unsigned short* WT2b = (unsigned short*)carve(65536 * 2);
  unsigned short* WT3b = (unsigned short*)carve(16384 * 2);
  int*   mode  = (int*)carve(256);
  const size_t NEED = o;   // ~161 MB

  if (ws_size < NEED) {  // decodable failure: absmax ≈ 77
    sentinel_k<<<4096, 256, 0, stream>>>(Zout, (long)out_size, 77.0f);
    return;
  }

  const int NCNT = NND + NED;                // 150000
  const int NBC = (NCNT + 255) / 256;        // 586
  const int FILL_GRID = (NNZC + 255) / 256;
  const int EG_GRID = (NED + 3) / 4;         // 12500
  const int NG_GRID = (NND + 3) / 4;         // 25000
  const int G3_GRID = (NND + 127) / 128;     // 782

  const int* voff = offAll;
  const int* eoff = offAll + NND;
  const int* degV = cntAll;
  const int* cntE = cntAll + NND;

  prep_f32<<<256, 256, 0, stream>>>(Hin, W1, W2, Wout, Hf, WT1b, WT2b, WT3b, mode);
  hipMemsetAsync(cntAll, 0, (size_t)NCNT * 4, stream);

  // ---- layer-1 GEMM with counting on dedicated blocks
  gemm1_cnt<<<CNTB + MGRID, 256, 0, stream>>>(Xin, mode, WT1b, (unsigned short*)XWb,
                                              NND, V, E, cntAll, rV, rE);

  scan_local<<<NBC, 256, 0, stream>>>(cntAll, offAll, bsum, NCNT);
  scan_add2<<<NBC, 256, 0, stream>>>(offAll, bsum, NCNT);
  fill_e<<<FILL_GRID, 256, 0, stream>>>(V, E, offAll, rE, eadj);

  // ---- layer 1 gathers; vadjH fill overlapped with edge gather
  edge_gather_b<<<FILLB + EG_GRID, 256, 0, stream>>>(
      eoff, cntE, eadj, XWb, Xeb, FILLB, V, E, offAll, rV, Hf, vadjH);
  node_gather_norm_b<<<NG_GRID, 256, 0, stream>>>(voff, degV, vadjH, Xeb, XWb,
                                                  Zb, nullptr);

  // ---- layer 2 (outputs: graded fp32 Zout + bf16 Zb for layer-3 GEMM)
  gemm_bf16_k<<<MGRID, 256, 0, stream>>>((const unsigned short*)Zb, WT2b,
                                         (unsigned short*)XWb, NND);
  edge_gather_b<<<EG_GRID, 256, 0, stream>>>(
      eoff, cntE, eadj, XWb, Xeb, 0, nullptr, nullptr, nullptr, nullptr, nullptr, nullptr);
  node_gather_norm_b<<<NG_GRID, 256, 0, stream>>>(voff, degV, vadjH, Xeb, XWb,
                                                  Zb, Zout);

  // ---- layer 3 (MFMA GEMM, bf16 intermediates, fp32 graded Xout)
  gemm3_mfma<<<G3_GRID, 256, 0, stream>>>((const unsigned short*)Zb, WT3b, XW64, NND);
  edge_gather_64<<<EG_GRID, 256, 0, stream>>>(eoff, cntE, eadj, XW64, Xe64);
  node_gather_norm_64<<<NG_GRID, 256, 0, stream>>>(voff, degV, vadjH, Xe64, XW64, Xout);
}